// Round 1
// 496.906 us; speedup vs baseline: 1.1261x; 1.1261x over previous
//
#include <hip/hip_runtime.h>
#include <hip/hip_bf16.h>

// out[b,s,o] = sum_d WHT(x)[b,s,d] * W[o,d] + bias[o]
// M = 8192, K = 4096, N = 4096. GEMM is B^T layout (W rows k-contiguous).

#define D_DIM 4096
#define M_ROWS 8192

typedef float f32x4 __attribute__((ext_vector_type(4)));
typedef __bf16 bf16x8 __attribute__((ext_vector_type(8)));

__device__ __forceinline__ unsigned short f2bf(float f) {
  unsigned int u = __float_as_uint(f);
  return (unsigned short)((u + 0x7fffu + ((u >> 16) & 1u)) >> 16);
}

__device__ __forceinline__ void async16(const void* g, void* l) {
  __builtin_amdgcn_global_load_lds(
      (const __attribute__((address_space(1))) unsigned int*)g,
      (__attribute__((address_space(3))) unsigned int*)l, 16, 0, 0);
}

// ---------------------------------------------------------------------------
// Kernel 1: per-row 4096-point WHT (normalized), fp32 in, bf16 out. Unchanged.
// ---------------------------------------------------------------------------
#define WHT_AS 280
#define WHT_BS 17

__global__ __launch_bounds__(256) void wht_cast_rows(
    const float* __restrict__ X, unsigned short* __restrict__ Y) {
  __shared__ float s[16 * WHT_AS];
  const int row = blockIdx.x;
  const float* xr = X + (size_t)row * D_DIM;
  const int t = threadIdx.x;
  float v[16];

#pragma unroll
  for (int a = 0; a < 16; ++a) v[a] = xr[a * 256 + t];
#pragma unroll
  for (int h = 1; h < 16; h <<= 1) {
#pragma unroll
    for (int i = 0; i < 16; ++i) {
      if ((i & h) == 0) {
        float p = v[i], q = v[i + h];
        v[i] = p + q;
        v[i + h] = p - q;
      }
    }
  }
  {
    const int base = (t >> 4) * WHT_BS + (t & 15);
#pragma unroll
    for (int a = 0; a < 16; ++a) s[a * WHT_AS + base] = v[a];
  }
  __syncthreads();

  {
    const int base = (t >> 4) * WHT_AS + (t & 15);
#pragma unroll
    for (int b = 0; b < 16; ++b) v[b] = s[base + b * WHT_BS];
#pragma unroll
    for (int h = 1; h < 16; h <<= 1) {
#pragma unroll
      for (int i = 0; i < 16; ++i) {
        if ((i & h) == 0) {
          float p = v[i], q = v[i + h];
          v[i] = p + q;
          v[i + h] = p - q;
        }
      }
    }
#pragma unroll
    for (int b = 0; b < 16; ++b) s[base + b * WHT_BS] = v[b];
  }
  __syncthreads();

  {
    const int base = (t >> 4) * WHT_AS + (t & 15) * WHT_BS;
#pragma unroll
    for (int c = 0; c < 16; ++c) v[c] = s[base + c];
#pragma unroll
    for (int h = 1; h < 16; h <<= 1) {
#pragma unroll
      for (int i = 0; i < 16; ++i) {
        if ((i & h) == 0) {
          float p = v[i], q = v[i + h];
          v[i] = p + q;
          v[i + h] = p - q;
        }
      }
    }
    union {
      unsigned short us[16];
      uint4 q4[2];
    } pk;
#pragma unroll
    for (int c = 0; c < 16; ++c) pk.us[c] = f2bf(v[c] * 0.015625f);
    uint4* dst =
        (uint4*)(Y + (size_t)row * D_DIM + (t >> 4) * 256 + (t & 15) * 16);
    dst[0] = pk.q4[0];
    dst[1] = pk.q4[1];
  }
}

// ---------------------------------------------------------------------------
// Kernel 2: W fp32 -> bf16 cast. Unchanged.
// ---------------------------------------------------------------------------
__global__ __launch_bounds__(256) void cast_w(const float* __restrict__ W,
                                              unsigned short* __restrict__ Wb) {
  const size_t i = ((size_t)blockIdx.x * 256 + threadIdx.x) * 8;
  const float4* p = (const float4*)(W + i);
  float4 f0 = p[0], f1 = p[1];
  union {
    unsigned short us[8];
    uint4 q;
  } pk;
  pk.us[0] = f2bf(f0.x);
  pk.us[1] = f2bf(f0.y);
  pk.us[2] = f2bf(f0.z);
  pk.us[3] = f2bf(f0.w);
  pk.us[4] = f2bf(f1.x);
  pk.us[5] = f2bf(f1.y);
  pk.us[6] = f2bf(f1.z);
  pk.us[7] = f2bf(f1.w);
  *(uint4*)(Wb + i) = pk.q;
}

// ---------------------------------------------------------------------------
// Kernel 3: 256x256 8-phase bf16 GEMM (B^T) + bias.
//  - BM=BN=256, BK=64, 512 threads = 8 waves (2 Mwaves x 4 Nwaves),
//    per-wave output 128x64, acc[8][4] of 16x16 frags.
//  - LDS 128 KiB: 2 dbuf x (A: 2 halves of 128x64 + B: 2 halves of 128x64).
//  - Half-tile layout: 16 subtiles of 16rows x 32cols (1024B each),
//    st_16x32 swizzle: short_off = stile*512 + rr*32 + (cc ^ ((rr>>3)<<4)).
//  - global_load_lds writes linearly; swizzle applied by pre-swizzling the
//    per-lane GLOBAL source (rule 21) and the same XOR on ds_read side.
//  - Per K-tile: P1 reads all 24 frags (frees all slots), then 4 phases of
//    16 MFMA with setprio; staging 1 half-tile/phase in order
//    {T+1.B1, T+2.A0, T+2.A1, T+2.B0}; single counted vmcnt(6) per tile.
// ---------------------------------------------------------------------------
#define GNT 64  // K / BK

__global__ __launch_bounds__(512, 2) void gemm256_bias(
    const unsigned short* __restrict__ A,  // [M][K] bf16 (x rotated)
    const unsigned short* __restrict__ B,  // [N][K] bf16 (W)
    const float* __restrict__ bias, float* __restrict__ C) {
  constexpr int K = 4096, N = 4096;
  __shared__ unsigned short sm[65536];  // 128 KiB

  const int tid = threadIdx.x;
  const int l = tid & 63;
  const int w = tid >> 6;      // wave 0..7
  const int wm = w >> 2;       // 0..1
  const int wn = w & 3;        // 0..3
  const int row16 = l & 15;
  const int kgrp = l >> 4;     // 0..3

  // T1: bijective XCD swizzle (512 % 8 == 0)
  const int orig = blockIdx.x;
  const int wgid = (orig & 7) * 64 + (orig >> 3);
  const int bn = wgid & 15;    // N/256 = 16
  const int bm = wgid >> 4;    // M/256 = 32
  const int m0 = bm * 256, n0 = bn * 256;

  // --- staging source (pre-swizzled per-lane global address) ---
  // thread t stages 16B at linear LDS off = h*8192 + j*4096 + t*8 (shorts);
  // that slot holds (row = j*64 + (w>>1)*16 + (l>>2),
  //                  col = (w&1)*32 + (((l&3)*16 ^ ((l>>5)<<5))>>1) .. +7)
  const int srcRow = (w >> 1) * 16 + (l >> 2);
  const int srcCol = (w & 1) * 32 + ((((l & 3) << 4) ^ ((l >> 5) << 5)) >> 1);
  const unsigned short* aS = A + (size_t)(m0 + srcRow) * K + srcCol;
  const unsigned short* bS = B + (size_t)(n0 + srcRow) * K + srcCol;
  const int dstBase = tid * 8;  // shorts

#define STG_A(b, h, kt)                                                       \
  do {                                                                        \
    async16(aS + (size_t)((h)*128) * K + (kt)*64,                             \
            &sm[(b)*32768 + (h)*8192 + dstBase]);                             \
    async16(aS + (size_t)((h)*128 + 64) * K + (kt)*64,                        \
            &sm[(b)*32768 + (h)*8192 + 4096 + dstBase]);                      \
  } while (0)
#define STG_B(b, h, kt)                                                       \
  do {                                                                        \
    async16(bS + (size_t)((h)*128) * K + (kt)*64,                             \
            &sm[(b)*32768 + 16384 + (h)*8192 + dstBase]);                     \
    async16(bS + (size_t)((h)*128 + 64) * K + (kt)*64,                        \
            &sm[(b)*32768 + 16384 + (h)*8192 + 4096 + dstBase]);              \
  } while (0)

  // --- ds_read lane offset (swizzled) ---
  const int laneRd = row16 * 32 + ((kgrp << 3) ^ ((row16 >> 3) << 4));

  f32x4 acc[8][4];
#pragma unroll
  for (int i = 0; i < 8; ++i)
#pragma unroll
    for (int j = 0; j < 4; ++j) acc[i][j] = (f32x4){0.f, 0.f, 0.f, 0.f};

  // Prologue: tile0 fully into buf0; tile1 {A0,A1,B0} into buf1.
  STG_A(0, 0, 0);
  STG_A(0, 1, 0);
  STG_B(0, 0, 0);
  STG_B(0, 1, 0);
  STG_A(1, 0, 1);
  STG_A(1, 1, 1);
  STG_B(1, 0, 1);
  asm volatile("s_waitcnt vmcnt(6)" ::: "memory");
  __builtin_amdgcn_s_barrier();

#define MFMA1(mf, nf, ks)                                             \
  acc[mf][nf] = __builtin_amdgcn_mfma_f32_16x16x32_bf16(              \
      af[mf][ks], bfm[nf][ks], acc[mf][nf], 0, 0, 0)
#define MFMA_GROUP(g)                                                 \
  MFMA1(2 * g + 0, 0, 0);                                             \
  MFMA1(2 * g + 0, 1, 0);                                             \
  MFMA1(2 * g + 0, 2, 0);                                             \
  MFMA1(2 * g + 0, 3, 0);                                             \
  MFMA1(2 * g + 1, 0, 0);                                             \
  MFMA1(2 * g + 1, 1, 0);                                             \
  MFMA1(2 * g + 1, 2, 0);                                             \
  MFMA1(2 * g + 1, 3, 0);                                             \
  MFMA1(2 * g + 0, 0, 1);                                             \
  MFMA1(2 * g + 0, 1, 1);                                             \
  MFMA1(2 * g + 0, 2, 1);                                             \
  MFMA1(2 * g + 0, 3, 1);                                             \
  MFMA1(2 * g + 1, 0, 1);                                             \
  MFMA1(2 * g + 1, 1, 1);                                             \
  MFMA1(2 * g + 1, 2, 1);                                             \
  MFMA1(2 * g + 1, 3, 1);

  int cur = 0;
  for (int T = 0; T < GNT; ++T) {
    const int base = cur * 32768;
    const unsigned short* pA = &sm[base + wm * 8192 + laneRd];
    const unsigned short* pB =
        &sm[base + 16384 + (wn >> 1) * 8192 + (wn & 1) * 4096 + laneRd];

    // ---- Phase 1: read ALL fragments of tile T, stage T+1.B1, MFMA g0
    bf16x8 af[8][2], bfm[4][2];
#pragma unroll
    for (int mf = 0; mf < 8; ++mf) {
      af[mf][0] = *(const bf16x8*)&pA[mf * 1024];
      af[mf][1] = *(const bf16x8*)&pA[mf * 1024 + 512];
    }
#pragma unroll
    for (int nf = 0; nf < 4; ++nf) {
      bfm[nf][0] = *(const bf16x8*)&pB[nf * 1024];
      bfm[nf][1] = *(const bf16x8*)&pB[nf * 1024 + 512];
    }
    if (T + 1 < GNT) STG_B(cur ^ 1, 1, T + 1);
    __builtin_amdgcn_s_barrier();
    asm volatile("s_waitcnt lgkmcnt(0)" ::: "memory");
    __builtin_amdgcn_s_setprio(1);
    MFMA_GROUP(0);
    __builtin_amdgcn_s_setprio(0);
    __builtin_amdgcn_s_barrier();

    // ---- Phase 2: stage T+2.A0 (slot free: all reads done in P1), MFMA g1
    if (T + 2 < GNT) STG_A(cur, 0, T + 2);
    __builtin_amdgcn_s_barrier();
    __builtin_amdgcn_s_setprio(1);
    MFMA_GROUP(1);
    __builtin_amdgcn_s_setprio(0);
    __builtin_amdgcn_s_barrier();

    // ---- Phase 3: stage T+2.A1, MFMA g2
    if (T + 2 < GNT) STG_A(cur, 1, T + 2);
    __builtin_amdgcn_s_barrier();
    __builtin_amdgcn_s_setprio(1);
    MFMA_GROUP(2);
    __builtin_amdgcn_s_setprio(0);
    __builtin_amdgcn_s_barrier();

    // ---- Phase 4: stage T+2.B0, MFMA g3, counted vmcnt, tile barrier
    if (T + 2 < GNT) STG_B(cur, 0, T + 2);
    __builtin_amdgcn_s_barrier();
    __builtin_amdgcn_s_setprio(1);
    MFMA_GROUP(3);
    __builtin_amdgcn_s_setprio(0);
    if (T < GNT - 2)
      asm volatile("s_waitcnt vmcnt(6)" ::: "memory");  // 3 half-tiles in flight
    else
      asm volatile("s_waitcnt vmcnt(0)" ::: "memory");  // epilogue drain
    __builtin_amdgcn_s_barrier();
    cur ^= 1;
  }

  // Epilogue: C/D layout col = lane&15, row = kgrp*4 + r
  const int mb = m0 + wm * 128 + kgrp * 4;
  const int nb = n0 + wn * 64 + row16;
  float bv[4];
#pragma unroll
  for (int nf = 0; nf < 4; ++nf) bv[nf] = bias[nb + nf * 16];
#pragma unroll
  for (int mf = 0; mf < 8; ++mf)
#pragma unroll
    for (int nf = 0; nf < 4; ++nf)
#pragma unroll
      for (int r = 0; r < 4; ++r)
        C[(size_t)(mb + mf * 16 + r) * N + nb + nf * 16] =
            acc[mf][nf][r] + bv[nf];
}

// ---------------------------------------------------------------------------
extern "C" void kernel_launch(void* const* d_in, const int* in_sizes, int n_in,
                              void* d_out, int out_size, void* d_ws,
                              size_t ws_size, hipStream_t stream) {
  const float* x = (const float*)d_in[0];
  const float* W = (const float*)d_in[1];
  const float* b = (const float*)d_in[2];
  float* out = (float*)d_out;

  unsigned short* Xr = (unsigned short*)d_ws;        // 64 MiB bf16
  unsigned short* Wb = Xr + (size_t)M_ROWS * D_DIM;  // 32 MiB bf16

  wht_cast_rows<<<M_ROWS, 256, 0, stream>>>(x, Xr);
  cast_w<<<(D_DIM * (size_t)D_DIM / 8) / 256, 256, 0, stream>>>(W, Wb);
  // 256x256 tiles: (8192/256) * (4096/256) = 32*16 = 512 blocks
  gemm256_bias<<<512, 512, 0, stream>>>(Xr, Wb, b, out);
}

// Round 2
// 486.424 us; speedup vs baseline: 1.1503x; 1.0215x over previous
//
#include <hip/hip_runtime.h>
#include <hip/hip_bf16.h>

// out[b,s,o] = sum_d WHT(x)[b,s,d] * W[o,d] + bias[o]
// M = 8192, K = 4096, N = 4096. GEMM is B^T layout (W rows k-contiguous).

#define D_DIM 4096
#define M_ROWS 8192

typedef float f32x4 __attribute__((ext_vector_type(4)));
typedef __bf16 bf16x8 __attribute__((ext_vector_type(8)));

__device__ __forceinline__ unsigned short f2bf(float f) {
  unsigned int u = __float_as_uint(f);
  return (unsigned short)((u + 0x7fffu + ((u >> 16) & 1u)) >> 16);
}

__device__ __forceinline__ void async16(const void* g, void* l) {
  __builtin_amdgcn_global_load_lds(
      (const __attribute__((address_space(1))) unsigned int*)g,
      (__attribute__((address_space(3))) unsigned int*)l, 16, 0, 0);
}

// ---------------------------------------------------------------------------
// Kernel 1: per-row 4096-point WHT (normalized), fp32 in, bf16 out. Unchanged.
// ---------------------------------------------------------------------------
#define WHT_AS 280
#define WHT_BS 17

__global__ __launch_bounds__(256) void wht_cast_rows(
    const float* __restrict__ X, unsigned short* __restrict__ Y) {
  __shared__ float s[16 * WHT_AS];
  const int row = blockIdx.x;
  const float* xr = X + (size_t)row * D_DIM;
  const int t = threadIdx.x;
  float v[16];

#pragma unroll
  for (int a = 0; a < 16; ++a) v[a] = xr[a * 256 + t];
#pragma unroll
  for (int h = 1; h < 16; h <<= 1) {
#pragma unroll
    for (int i = 0; i < 16; ++i) {
      if ((i & h) == 0) {
        float p = v[i], q = v[i + h];
        v[i] = p + q;
        v[i + h] = p - q;
      }
    }
  }
  {
    const int base = (t >> 4) * WHT_BS + (t & 15);
#pragma unroll
    for (int a = 0; a < 16; ++a) s[a * WHT_AS + base] = v[a];
  }
  __syncthreads();

  {
    const int base = (t >> 4) * WHT_AS + (t & 15);
#pragma unroll
    for (int b = 0; b < 16; ++b) v[b] = s[base + b * WHT_BS];
#pragma unroll
    for (int h = 1; h < 16; h <<= 1) {
#pragma unroll
      for (int i = 0; i < 16; ++i) {
        if ((i & h) == 0) {
          float p = v[i], q = v[i + h];
          v[i] = p + q;
          v[i + h] = p - q;
        }
      }
    }
#pragma unroll
    for (int b = 0; b < 16; ++b) s[base + b * WHT_BS] = v[b];
  }
  __syncthreads();

  {
    const int base = (t >> 4) * WHT_AS + (t & 15) * WHT_BS;
#pragma unroll
    for (int c = 0; c < 16; ++c) v[c] = s[base + c];
#pragma unroll
    for (int h = 1; h < 16; h <<= 1) {
#pragma unroll
      for (int i = 0; i < 16; ++i) {
        if ((i & h) == 0) {
          float p = v[i], q = v[i + h];
          v[i] = p + q;
          v[i + h] = p - q;
        }
      }
    }
    union {
      unsigned short us[16];
      uint4 q4[2];
    } pk;
#pragma unroll
    for (int c = 0; c < 16; ++c) pk.us[c] = f2bf(v[c] * 0.015625f);
    uint4* dst =
        (uint4*)(Y + (size_t)row * D_DIM + (t >> 4) * 256 + (t & 15) * 16);
    dst[0] = pk.q4[0];
    dst[1] = pk.q4[1];
  }
}

// ---------------------------------------------------------------------------
// Kernel 2: W fp32 -> bf16 cast. Unchanged.
// ---------------------------------------------------------------------------
__global__ __launch_bounds__(256) void cast_w(const float* __restrict__ W,
                                              unsigned short* __restrict__ Wb) {
  const size_t i = ((size_t)blockIdx.x * 256 + threadIdx.x) * 8;
  const float4* p = (const float4*)(W + i);
  float4 f0 = p[0], f1 = p[1];
  union {
    unsigned short us[8];
    uint4 q;
  } pk;
  pk.us[0] = f2bf(f0.x);
  pk.us[1] = f2bf(f0.y);
  pk.us[2] = f2bf(f0.z);
  pk.us[3] = f2bf(f0.w);
  pk.us[4] = f2bf(f1.x);
  pk.us[5] = f2bf(f1.y);
  pk.us[6] = f2bf(f1.z);
  pk.us[7] = f2bf(f1.w);
  *(uint4*)(Wb + i) = pk.q;
}

// ---------------------------------------------------------------------------
// Kernel 3: 256x256 8-phase bf16 GEMM (B^T) + bias.
//  - BM=BN=256, BK=64, 512 threads = 8 waves (2 Mwaves x 4 Nwaves),
//    per-wave output 128x64, acc[8][4] of 16x16 frags.
//  - LDS 128 KiB: 2 dbuf x (A: 2 halves of 128x64 + B: 2 halves of 128x64).
//  - st_16x32 swizzle via pre-swizzled global source + swizzled ds_read.
//  - PER-PHASE interleave (m196): each phase = {ds_read subtile, stage one
//    half-tile, barrier, lgkmcnt(0), setprio+16 MFMA, barrier}.
//    P1: read af[0..3]+bfm[0..1] (12), stage T+1.B0->buf^1, g0=af03 x bf01
//    P2: read af[4..7]+bfm[2..3] (12), stage T+1.B1->buf^1, g1=af47 x bf01
//    P3: (regs reused)              stage T+2.A0->buf,    g2=af03 x bf23
//    P4: (regs reused)              stage T+2.A1->buf,    g3=af47 x bf23
//    A-region reads complete by P2-end barrier -> P3/P4 A-stages race-free.
//  - Boundary wait: outstanding = {T+1.A0,A1 (from T-1 P3/P4), T+1.B0,B1,
//    T+2.A0,A1} = 12 loads; vmcnt(4) drains the oldest 8 = all of T+1;
//    2 half-tiles stay in flight. vmcnt(0) only for the last two tiles.
// ---------------------------------------------------------------------------
#define GNT 64  // K / BK

__global__ __launch_bounds__(512, 2) void gemm256_bias(
    const unsigned short* __restrict__ A,  // [M][K] bf16 (x rotated)
    const unsigned short* __restrict__ B,  // [N][K] bf16 (W)
    const float* __restrict__ bias, float* __restrict__ C) {
  constexpr int K = 4096, N = 4096;
  __shared__ unsigned short sm[65536];  // 128 KiB

  const int tid = threadIdx.x;
  const int l = tid & 63;
  const int w = tid >> 6;      // wave 0..7
  const int wm = w >> 2;       // 0..1
  const int wn = w & 3;        // 0..3
  const int row16 = l & 15;
  const int kgrp = l >> 4;     // 0..3

  // T1: bijective XCD swizzle (512 % 8 == 0)
  const int orig = blockIdx.x;
  const int wgid = (orig & 7) * 64 + (orig >> 3);
  const int bn = wgid & 15;    // N/256 = 16
  const int bm = wgid >> 4;    // M/256 = 32
  const int m0 = bm * 256, n0 = bn * 256;

  // staging source (pre-swizzled per-lane global address)
  const int srcRow = (w >> 1) * 16 + (l >> 2);
  const int srcCol = (w & 1) * 32 + ((((l & 3) << 4) ^ ((l >> 5) << 5)) >> 1);
  const unsigned short* aS = A + (size_t)(m0 + srcRow) * K + srcCol;
  const unsigned short* bS = B + (size_t)(n0 + srcRow) * K + srcCol;
  const int dstBase = tid * 8;  // shorts

#define STG_A(b, h, kt)                                                       \
  do {                                                                        \
    async16(aS + (size_t)((h)*128) * K + (kt)*64,                             \
            &sm[(b)*32768 + (h)*8192 + dstBase]);                             \
    async16(aS + (size_t)((h)*128 + 64) * K + (kt)*64,                        \
            &sm[(b)*32768 + (h)*8192 + 4096 + dstBase]);                      \
  } while (0)
#define STG_B(b, h, kt)                                                       \
  do {                                                                        \
    async16(bS + (size_t)((h)*128) * K + (kt)*64,                             \
            &sm[(b)*32768 + 16384 + (h)*8192 + dstBase]);                     \
    async16(bS + (size_t)((h)*128 + 64) * K + (kt)*64,                        \
            &sm[(b)*32768 + 16384 + (h)*8192 + 4096 + dstBase]);              \
  } while (0)

  // ds_read lane offset (swizzled)
  const int laneRd = row16 * 32 + ((kgrp << 3) ^ ((row16 >> 3) << 4));

  f32x4 acc[8][4];
#pragma unroll
  for (int i = 0; i < 8; ++i)
#pragma unroll
    for (int j = 0; j < 4; ++j) acc[i][j] = (f32x4){0.f, 0.f, 0.f, 0.f};

  // Prologue: tile0 fully into buf0; tile1 {A0,A1} into buf1.
  STG_A(0, 0, 0);
  STG_A(0, 1, 0);
  STG_B(0, 0, 0);
  STG_B(0, 1, 0);
  STG_A(1, 0, 1);
  STG_A(1, 1, 1);
  asm volatile("s_waitcnt vmcnt(4)" ::: "memory");  // tile0 landed
  __builtin_amdgcn_s_barrier();

  // 16 MFMAs: acc[MB..MB+3][NB..NB+1] over ks=0..1
#define MFMA_G(MB, NB)                                                       \
  _Pragma("unroll") for (int ks = 0; ks < 2; ++ks)                           \
      _Pragma("unroll") for (int mf = 0; mf < 4; ++mf)                       \
          _Pragma("unroll") for (int nf = 0; nf < 2; ++nf) acc[MB + mf]      \
              [NB + nf] = __builtin_amdgcn_mfma_f32_16x16x32_bf16(           \
                  af[MB + mf][ks], bfm[NB + nf][ks], acc[MB + mf][NB + nf],  \
                  0, 0, 0);

  int cur = 0;
  for (int T = 0; T < GNT; ++T) {
    const int base = cur * 32768;
    const unsigned short* pA = &sm[base + wm * 8192 + laneRd];
    const unsigned short* pB =
        &sm[base + 16384 + (wn >> 1) * 8192 + (wn & 1) * 4096 + laneRd];
    bf16x8 af[8][2], bfm[4][2];

    // ---- Phase 1: read af[0..3], bfm[0..1]; stage T+1.B0 -> buf^1; g0
#pragma unroll
    for (int mf = 0; mf < 4; ++mf) {
      af[mf][0] = *(const bf16x8*)&pA[mf * 1024];
      af[mf][1] = *(const bf16x8*)&pA[mf * 1024 + 512];
    }
#pragma unroll
    for (int nf = 0; nf < 2; ++nf) {
      bfm[nf][0] = *(const bf16x8*)&pB[nf * 1024];
      bfm[nf][1] = *(const bf16x8*)&pB[nf * 1024 + 512];
    }
    if (T + 1 < GNT) STG_B(cur ^ 1, 0, T + 1);
    asm volatile("s_waitcnt lgkmcnt(8)" ::: "memory");
    __builtin_amdgcn_s_barrier();
    asm volatile("s_waitcnt lgkmcnt(0)" ::: "memory");
    __builtin_amdgcn_s_setprio(1);
    MFMA_G(0, 0);
    __builtin_amdgcn_s_setprio(0);
    __builtin_amdgcn_s_barrier();

    // ---- Phase 2: read af[4..7], bfm[2..3]; stage T+1.B1 -> buf^1; g1
#pragma unroll
    for (int mf = 4; mf < 8; ++mf) {
      af[mf][0] = *(const bf16x8*)&pA[mf * 1024];
      af[mf][1] = *(const bf16x8*)&pA[mf * 1024 + 512];
    }
#pragma unroll
    for (int nf = 2; nf < 4; ++nf) {
      bfm[nf][0] = *(const bf16x8*)&pB[nf * 1024];
      bfm[nf][1] = *(const bf16x8*)&pB[nf * 1024 + 512];
    }
    if (T + 1 < GNT) STG_B(cur ^ 1, 1, T + 1);
    asm volatile("s_waitcnt lgkmcnt(8)" ::: "memory");
    __builtin_amdgcn_s_barrier();
    asm volatile("s_waitcnt lgkmcnt(0)" ::: "memory");
    __builtin_amdgcn_s_setprio(1);
    MFMA_G(4, 0);
    __builtin_amdgcn_s_setprio(0);
    __builtin_amdgcn_s_barrier();
    // All A-region (and B-region) reads of buf cur are now retired.

    // ---- Phase 3: stage T+2.A0 -> buf cur; g2
    if (T + 2 < GNT) STG_A(cur, 0, T + 2);
    __builtin_amdgcn_s_barrier();
    __builtin_amdgcn_s_setprio(1);
    MFMA_G(0, 2);
    __builtin_amdgcn_s_setprio(0);
    __builtin_amdgcn_s_barrier();

    // ---- Phase 4: stage T+2.A1 -> buf cur; g3; counted vmcnt; tile barrier
    if (T + 2 < GNT) STG_A(cur, 1, T + 2);
    __builtin_amdgcn_s_barrier();
    __builtin_amdgcn_s_setprio(1);
    MFMA_G(4, 2);
    __builtin_amdgcn_s_setprio(0);
    if (T < GNT - 2)
      asm volatile("s_waitcnt vmcnt(4)" ::: "memory");  // T+1 fully landed
    else
      asm volatile("s_waitcnt vmcnt(0)" ::: "memory");  // epilogue drain
    __builtin_amdgcn_s_barrier();
    cur ^= 1;
  }

  // Epilogue: C/D layout col = lane&15, row = kgrp*4 + r
  const int mb = m0 + wm * 128 + kgrp * 4;
  const int nb = n0 + wn * 64 + row16;
  float bv[4];
#pragma unroll
  for (int nf = 0; nf < 4; ++nf) bv[nf] = bias[nb + nf * 16];
#pragma unroll
  for (int mf = 0; mf < 8; ++mf)
#pragma unroll
    for (int nf = 0; nf < 4; ++nf)
#pragma unroll
      for (int r = 0; r < 4; ++r)
        C[(size_t)(mb + mf * 16 + r) * N + nb + nf * 16] =
            acc[mf][nf][r] + bv[nf];
}

// ---------------------------------------------------------------------------
extern "C" void kernel_launch(void* const* d_in, const int* in_sizes, int n_in,
                              void* d_out, int out_size, void* d_ws,
                              size_t ws_size, hipStream_t stream) {
  const float* x = (const float*)d_in[0];
  const float* W = (const float*)d_in[1];
  const float* b = (const float*)d_in[2];
  float* out = (float*)d_out;

  unsigned short* Xr = (unsigned short*)d_ws;        // 64 MiB bf16
  unsigned short* Wb = Xr + (size_t)M_ROWS * D_DIM;  // 32 MiB bf16

  wht_cast_rows<<<M_ROWS, 256, 0, stream>>>(x, Xr);
  cast_w<<<(D_DIM * (size_t)D_DIM / 8) / 256, 256, 0, stream>>>(W, Wb);
  // 256x256 tiles: (8192/256) * (4096/256) = 32*16 = 512 blocks
  gemm256_bias<<<512, 512, 0, stream>>>(Xr, Wb, b, out);
}